// Round 3
// baseline (2757.266 us; speedup 1.0000x reference)
//
#include <hip/hip_runtime.h>
#include <math.h>

#define N_NODES 100000
#define N_EDGES 1600000
#define SCAN_BS 256

__device__ __forceinline__ float sigmoidf_(float x){ return 1.f/(1.f + expf(-x)); }
__device__ __forceinline__ float eluf_(float x){ return x > 0.f ? x : expm1f(x); }

// ---------------- CSR build (dst-sorted edge lists) ----------------
__global__ void zero_counts(int* cnt, int* cur, int n){
  int i = blockIdx.x*blockDim.x + threadIdx.x;
  if (i < n){ cnt[i]=0; cur[i]=0; }
}
__global__ void count_kernel(const int* __restrict__ ei, int* __restrict__ cnt, int e){
  int i = blockIdx.x*blockDim.x + threadIdx.x;
  if (i < e) atomicAdd(&cnt[ei[N_EDGES + i]], 1);
}
// hierarchical exclusive scan of cnt[0..n) -> row_start[0..n]
__global__ void scan1_kernel(const int* __restrict__ cnt, int* __restrict__ pre,
                             int* __restrict__ bsum, int n){
  __shared__ int sh[SCAN_BS];
  int t = threadIdx.x, gi = blockIdx.x*SCAN_BS + t;
  int v = (gi < n) ? cnt[gi] : 0;
  sh[t] = v;
  __syncthreads();
  for (int off=1; off<SCAN_BS; off<<=1){
    int u = (t>=off)?sh[t-off]:0;
    __syncthreads();
    sh[t] += u;
    __syncthreads();
  }
  if (gi < n) pre[gi] = sh[t] - v;          // exclusive within block
  if (t == SCAN_BS-1) bsum[blockIdx.x] = sh[t];
}
__global__ void scan2_kernel(int* __restrict__ bsum, int nb){
  __shared__ int sh[1024];
  int t = threadIdx.x;
  int v = (t < nb) ? bsum[t] : 0;
  sh[t] = v;
  __syncthreads();
  for (int off=1; off<1024; off<<=1){
    int u = (t>=off)?sh[t-off]:0;
    __syncthreads();
    sh[t] += u;
    __syncthreads();
  }
  if (t < nb) bsum[t] = sh[t] - v;          // exclusive block offsets
}
__global__ void scan3_kernel(const int* __restrict__ pre, const int* __restrict__ bsum,
                             int* __restrict__ row_start, int n){
  int i = blockIdx.x*blockDim.x + threadIdx.x;
  if (i < n) row_start[i] = pre[i] + bsum[i/SCAN_BS];
  if (i == 0) row_start[n] = N_EDGES;
}
__global__ void scatter_kernel(const int* __restrict__ ei, const float* __restrict__ ea,
    const int* __restrict__ row_start, int* __restrict__ cur,
    int* __restrict__ ssrc, float* __restrict__ sew, int e){
  int i = blockIdx.x*blockDim.x + threadIdx.x;
  if (i < e){
    int d = ei[N_EDGES + i];
    int p = row_start[d] + atomicAdd(&cur[d], 1);
    ssrc[p] = ei[i];
    sew[p] = ea[i];
  }
}

// ---------------- elementwise ----------------
__global__ void pad_x_kernel(const float* __restrict__ x, float* __restrict__ h, int n){
  int i = blockIdx.x*blockDim.x + threadIdx.x; // over n*32
  if (i < n*32){
    int node = i >> 5, c = i & 31;
    h[i] = (c < 16) ? x[node*16 + c] : 0.f;
  }
}
__global__ void transition_kernel(const float* __restrict__ h1, float* __restrict__ h2, int n){
  int i = blockIdx.x*blockDim.x + threadIdx.x; // over n*64
  if (i < n*64){
    int node = i >> 6, c = i & 63;
    h2[i] = (c < 32) ? eluf_(h1[node*32 + c]) : 0.f;
  }
}

// ---------------- m = h @ W  (C x C): one node per lane, output-stationary ----
// Weight row W[k*C + c], k uniform-per-iteration -> scalar loads (s_load),
// accumulators out[C] statically indexed -> stay in VGPRs. No LDS.
template<int C>
__global__ __launch_bounds__(256) void mgemm_kernel(const float* __restrict__ hin,
    const float* __restrict__ W, float* __restrict__ mout, int n){
  int node = blockIdx.x*256 + threadIdx.x;
  bool valid = node < n;
  int nidx = valid ? node : (n-1);
  const float* hrow = hin + (size_t)nidx*C;
  float out[C];
  #pragma unroll
  for (int c=0;c<C;c++) out[c]=0.f;
  for (int k=0;k<C;k++){
    float hk = hrow[k];
    const float* wrow = W + k*C;         // uniform address -> scalar stream
    #pragma unroll
    for (int c=0;c<C;c++)
      out[c] = fmaf(hk, wrow[c], out[c]);
  }
  if (valid){
    float4* mp = (float4*)(mout + (size_t)node*C);
    #pragma unroll
    for (int q=0;q<C/4;q++){
      float4 v; v.x=out[4*q]; v.y=out[4*q+1]; v.z=out[4*q+2]; v.w=out[4*q+3];
      mp[q]=v;
    }
  }
}

// ---------------- agg[n][c] = max over incoming edges of m[src][c]*ew, else 0 ----------------
template<int C>
__global__ void agg_kernel(const float* __restrict__ m, const int* __restrict__ row_start,
    const int* __restrict__ ssrc, const float* __restrict__ sew,
    float* __restrict__ agg, int n_nodes){
  int gid = blockIdx.x*blockDim.x + threadIdx.x;
  int nn = gid / C, c = gid % C;
  if (nn >= n_nodes) return;
  int s = row_start[nn], e = row_start[nn+1];
  float acc = -__builtin_inff();
  for (int i=s;i<e;i++){
    int src = ssrc[i];
    float w = sew[i];
    acc = fmaxf(acc, m[src*C + c]*w);
  }
  agg[nn*C+c] = (e > s) ? acc : 0.f;
}

// ---------------- fused GRU cell: h = GRU(agg, h) — one node per lane ----------
// agg/h rows in registers (static indexing via full k-unroll); 6 gate rows of
// Wih/Whh read at uniform addresses -> scalar pipe. No LDS, no staging.
// In-place safe: each thread reads its own row element c before writing it.
template<int C>
__global__ __launch_bounds__(256) void gru_kernel(
    const float* __restrict__ agg, const float* __restrict__ hin,
    const float* __restrict__ Wih, const float* __restrict__ Whh,
    const float* __restrict__ bih, const float* __restrict__ bhh,
    float* __restrict__ hout, int n_nodes){
  int node = blockIdx.x*256 + threadIdx.x;
  bool valid = node < n_nodes;
  int nidx = valid ? node : (n_nodes-1);
  float a[C], hh[C];
  const float4* ap = (const float4*)(agg + (size_t)nidx*C);
  const float4* hp = (const float4*)(hin + (size_t)nidx*C);
  #pragma unroll
  for (int q=0;q<C/4;q++){
    float4 v = ap[q]; a[4*q]=v.x; a[4*q+1]=v.y; a[4*q+2]=v.z; a[4*q+3]=v.w;
    float4 u = hp[q]; hh[4*q]=u.x; hh[4*q+1]=u.y; hh[4*q+2]=u.z; hh[4*q+3]=u.w;
  }
  const float* hrow = hin + (size_t)nidx*C;
  for (int c=0;c<C;c++){
    float gR = bih[c], gZ = bih[c+C], gN = bih[c+2*C];
    float hR = bhh[c], hZ = bhh[c+C], hN = bhh[c+2*C];
    const float* wiR = Wih + (size_t)c*C;
    const float* wiZ = Wih + (size_t)(c+C)*C;
    const float* wiN = Wih + (size_t)(c+2*C)*C;
    const float* whR = Whh + (size_t)c*C;
    const float* whZ = Whh + (size_t)(c+C)*C;
    const float* whN = Whh + (size_t)(c+2*C)*C;
    #pragma unroll
    for (int k=0;k<C;k++){
      gR = fmaf(a[k],  wiR[k], gR);
      gZ = fmaf(a[k],  wiZ[k], gZ);
      gN = fmaf(a[k],  wiN[k], gN);
      hR = fmaf(hh[k], whR[k], hR);
      hZ = fmaf(hh[k], whZ[k], hZ);
      hN = fmaf(hh[k], whN[k], hN);
    }
    float r  = sigmoidf_(gR + hR);
    float z  = sigmoidf_(gZ + hZ);
    float nn = tanhf(gN + r*hN);
    float hc = hrow[c];                 // L1/L2 reload (avoids runtime reg index)
    if (valid) hout[(size_t)node*C + c] = (1.f - z)*nn + z*hc;
  }
}

// ---------------- head: elu -> fc1 -> elu -> fc2 -> log_softmax — one node per lane ----
__global__ __launch_bounds__(256) void head_kernel(const float* __restrict__ h2,
   const float* __restrict__ fc1w, const float* __restrict__ fc1b,
   const float* __restrict__ fc2w, const float* __restrict__ fc2b,
   float* __restrict__ out, int n){
  int node = blockIdx.x*256 + threadIdx.x;
  bool valid = node < n;
  int nidx = valid ? node : (n-1);
  float h[64];
  const float4* hp = (const float4*)(h2 + (size_t)nidx*64);
  #pragma unroll
  for (int q=0;q<16;q++){
    float4 v = hp[q];
    h[4*q]=eluf_(v.x); h[4*q+1]=eluf_(v.y); h[4*q+2]=eluf_(v.z); h[4*q+3]=eluf_(v.w);
  }
  float lg[10];
  #pragma unroll
  for (int c=0;c<10;c++) lg[c]=fc2b[c];
  for (int j=0;j<128;j++){
    float s = fc1b[j];
    const float* wrow = fc1w + (size_t)j*64;   // uniform -> scalar stream
    #pragma unroll
    for (int k=0;k<64;k++) s = fmaf(h[k], wrow[k], s);
    float e = eluf_(s);
    #pragma unroll
    for (int c=0;c<10;c++) lg[c] = fmaf(e, fc2w[(size_t)c*128 + j], lg[c]);
  }
  if (valid){
    float mx = lg[0];
    #pragma unroll
    for (int c=1;c<10;c++) mx = fmaxf(mx, lg[c]);
    float s = 0.f;
    #pragma unroll
    for (int c=0;c<10;c++) s += expf(lg[c]-mx);
    float lse = mx + logf(s);
    #pragma unroll
    for (int c=0;c<10;c++) out[(size_t)node*10+c] = lg[c]-lse;
  }
}

extern "C" void kernel_launch(void* const* d_in, const int* in_sizes, int n_in,
                              void* d_out, int out_size, void* d_ws, size_t ws_size,
                              hipStream_t stream){
  const float* x    = (const float*)d_in[0];
  const int*   ei   = (const int*)  d_in[1];
  const float* ea   = (const float*)d_in[2];
  const float* W1   = (const float*)d_in[3];
  const float* Wih1 = (const float*)d_in[4];
  const float* Whh1 = (const float*)d_in[5];
  const float* bih1 = (const float*)d_in[6];
  const float* bhh1 = (const float*)d_in[7];
  const float* W2   = (const float*)d_in[8];
  const float* Wih2 = (const float*)d_in[9];
  const float* Whh2 = (const float*)d_in[10];
  const float* bih2 = (const float*)d_in[11];
  const float* bhh2 = (const float*)d_in[12];
  const float* fc1w = (const float*)d_in[13];
  const float* fc1b = (const float*)d_in[14];
  const float* fc2w = (const float*)d_in[15];
  const float* fc2b = (const float*)d_in[16];
  float* outp = (float*)d_out;

  char* ws = (char*)d_ws;
  size_t off = 0;
  auto alloc = [&](size_t bytes)->void*{
    void* p = ws + off;
    off += (bytes + 255) & ~size_t(255);
    return p;
  };
  float* hA        = (float*)alloc(sizeof(float)*N_NODES*64);
  float* hB        = (float*)alloc(sizeof(float)*N_NODES*64);
  float* mB        = (float*)alloc(sizeof(float)*N_NODES*64);
  float* aggB      = (float*)alloc(sizeof(float)*N_NODES*64);
  int*   row_start = (int*)  alloc(sizeof(int)*(N_NODES+1));
  int*   cnt       = (int*)  alloc(sizeof(int)*N_NODES);
  int*   cur       = (int*)  alloc(sizeof(int)*N_NODES);
  int*   pre       = (int*)  alloc(sizeof(int)*N_NODES);
  int*   bsum      = (int*)  alloc(sizeof(int)*1024);
  int*   ssrc      = (int*)  alloc(sizeof(int)*N_EDGES);
  float* sew       = (float*)alloc(sizeof(float)*N_EDGES);
  (void)ws_size; (void)in_sizes; (void)n_in; (void)out_size;

  const int n = N_NODES, e = N_EDGES;
  const int nb = (n + SCAN_BS - 1)/SCAN_BS;   // 391 blocks

  // CSR build (per call; max-agg is order-invariant so atomic ordering is fine)
  zero_counts<<<(n+255)/256,256,0,stream>>>(cnt, cur, n);
  count_kernel<<<(e+255)/256,256,0,stream>>>(ei, cnt, e);
  scan1_kernel<<<nb,SCAN_BS,0,stream>>>(cnt, pre, bsum, n);
  scan2_kernel<<<1,1024,0,stream>>>(bsum, nb);
  scan3_kernel<<<(n+255)/256,256,0,stream>>>(pre, bsum, row_start, n);
  scatter_kernel<<<(e+255)/256,256,0,stream>>>(ei, ea, row_start, cur, ssrc, sew, e);

  const int nblk = (n+255)/256;

  // layer 1 (C=32)
  pad_x_kernel<<<(n*32+255)/256,256,0,stream>>>(x, hA, n);
  for (int i=0;i<3;i++){
    mgemm_kernel<32><<<nblk,256,0,stream>>>(hA, W1 + i*32*32, mB, n);
    agg_kernel<32><<<((long long)n*32+255)/256,256,0,stream>>>(mB, row_start, ssrc, sew, aggB, n);
    gru_kernel<32><<<nblk,256,0,stream>>>(aggB, hA, Wih1, Whh1, bih1, bhh1, hA, n);
  }

  // transition: elu + pad 32 -> 64
  transition_kernel<<<(n*64+255)/256,256,0,stream>>>(hA, hB, n);

  // layer 2 (C=64)
  for (int i=0;i<3;i++){
    mgemm_kernel<64><<<nblk,256,0,stream>>>(hB, W2 + i*64*64, mB, n);
    agg_kernel<64><<<((long long)n*64+255)/256,256,0,stream>>>(mB, row_start, ssrc, sew, aggB, n);
    gru_kernel<64><<<nblk,256,0,stream>>>(aggB, hB, Wih2, Whh2, bih2, bhh2, hB, n);
  }

  // head
  head_kernel<<<nblk,256,0,stream>>>(hB, fc1w, fc1b, fc2w, fc2b, outp, n);
}

// Round 4
// 1577.341 us; speedup vs baseline: 1.7480x; 1.7480x over previous
//
#include <hip/hip_runtime.h>
#include <math.h>

#define N_NODES 100000
#define N_EDGES 1600000
#define SCAN_BS 256

__device__ __forceinline__ float sigmoidf_(float x){ return 1.f/(1.f + expf(-x)); }
__device__ __forceinline__ float eluf_(float x){ return x > 0.f ? x : expm1f(x); }

// ---------------- CSR build (dst-sorted edge lists) ----------------
__global__ void zero_counts(int* cnt, int* cur, int n){
  int i = blockIdx.x*blockDim.x + threadIdx.x;
  if (i < n){ cnt[i]=0; cur[i]=0; }
}
__global__ void count_kernel(const int* __restrict__ ei, int* __restrict__ cnt, int e){
  int i = blockIdx.x*blockDim.x + threadIdx.x;
  if (i < e) atomicAdd(&cnt[ei[N_EDGES + i]], 1);
}
// hierarchical exclusive scan of cnt[0..n) -> row_start[0..n]
__global__ void scan1_kernel(const int* __restrict__ cnt, int* __restrict__ pre,
                             int* __restrict__ bsum, int n){
  __shared__ int sh[SCAN_BS];
  int t = threadIdx.x, gi = blockIdx.x*SCAN_BS + t;
  int v = (gi < n) ? cnt[gi] : 0;
  sh[t] = v;
  __syncthreads();
  for (int off=1; off<SCAN_BS; off<<=1){
    int u = (t>=off)?sh[t-off]:0;
    __syncthreads();
    sh[t] += u;
    __syncthreads();
  }
  if (gi < n) pre[gi] = sh[t] - v;          // exclusive within block
  if (t == SCAN_BS-1) bsum[blockIdx.x] = sh[t];
}
__global__ void scan2_kernel(int* __restrict__ bsum, int nb){
  __shared__ int sh[1024];
  int t = threadIdx.x;
  int v = (t < nb) ? bsum[t] : 0;
  sh[t] = v;
  __syncthreads();
  for (int off=1; off<1024; off<<=1){
    int u = (t>=off)?sh[t-off]:0;
    __syncthreads();
    sh[t] += u;
    __syncthreads();
  }
  if (t < nb) bsum[t] = sh[t] - v;          // exclusive block offsets
}
__global__ void scan3_kernel(const int* __restrict__ pre, const int* __restrict__ bsum,
                             int* __restrict__ row_start, int n){
  int i = blockIdx.x*blockDim.x + threadIdx.x;
  if (i < n) row_start[i] = pre[i] + bsum[i/SCAN_BS];
  if (i == 0) row_start[n] = N_EDGES;
}
__global__ void scatter_kernel(const int* __restrict__ ei, const float* __restrict__ ea,
    const int* __restrict__ row_start, int* __restrict__ cur,
    int* __restrict__ ssrc, float* __restrict__ sew, int e){
  int i = blockIdx.x*blockDim.x + threadIdx.x;
  if (i < e){
    int d = ei[N_EDGES + i];
    int p = row_start[d] + atomicAdd(&cur[d], 1);
    ssrc[p] = ei[i];
    sew[p] = ea[i];
  }
}

// ---------------- elementwise ----------------
__global__ void pad_x_kernel(const float* __restrict__ x, float* __restrict__ h, int n){
  int i = blockIdx.x*blockDim.x + threadIdx.x; // over n*32
  if (i < n*32){
    int node = i >> 5, c = i & 31;
    h[i] = (c < 16) ? x[node*16 + c] : 0.f;
  }
}
__global__ void transition_kernel(const float* __restrict__ h1, float* __restrict__ h2, int n){
  int i = blockIdx.x*blockDim.x + threadIdx.x; // over n*64
  if (i < n*64){
    int node = i >> 6, c = i & 63;
    h2[i] = (c < 32) ? eluf_(h1[node*32 + c]) : 0.f;
  }
}

// ---------------- m = h @ W  (C x C), 256 threads (R1-proven) ----------------
template<int C, int NT>
__global__ __launch_bounds__(256) void mgemm_kernel(const float* __restrict__ hin,
    const float* __restrict__ W, float* __restrict__ mout, int n){
  constexpr int HC = C/2;
  constexpr int G = 256/HC;
  constexpr int NB = G*NT;
  __shared__ float Wl[C*C];
  __shared__ float stage[NB*C];
  int tid = threadIdx.x;
  int cc = tid % HC, g = tid / HC;
  int base = blockIdx.x * NB;
  for (int idx=tid; idx<C*C; idx+=256) Wl[idx] = W[idx];
  for (int idx=tid; idx<NB*C; idx+=256){
    int node = base + idx / C;
    stage[idx] = (node < n) ? hin[node*C + (idx % C)] : 0.f;
  }
  __syncthreads();
  float acc[NT][2];
  #pragma unroll
  for(int j=0;j<NT;j++){acc[j][0]=0.f;acc[j][1]=0.f;}
  for (int k=0;k<C;k++){
    float w0 = Wl[k*C+cc], w1 = Wl[k*C+cc+HC];
    #pragma unroll
    for (int j=0;j<NT;j++){
      float a = stage[(g*NT+j)*C + k];
      acc[j][0] = fmaf(a,w0,acc[j][0]);
      acc[j][1] = fmaf(a,w1,acc[j][1]);
    }
  }
  #pragma unroll
  for (int j=0;j<NT;j++){
    int node = base + g*NT + j;
    if (node < n){
      mout[node*C + cc]      = acc[j][0];
      mout[node*C + cc + HC] = acc[j][1];
    }
  }
}

// ---------------- agg[n][c] = max over incoming edges of m[src][c]*ew, else 0 ----------------
template<int C>
__global__ void agg_kernel(const float* __restrict__ m, const int* __restrict__ row_start,
    const int* __restrict__ ssrc, const float* __restrict__ sew,
    float* __restrict__ agg, int n_nodes){
  int gid = blockIdx.x*blockDim.x + threadIdx.x;
  int nn = gid / C, c = gid % C;
  if (nn >= n_nodes) return;
  int s = row_start[nn], e = row_start[nn+1];
  float acc = -__builtin_inff();
  for (int i=s;i<e;i++){
    int src = ssrc[i];
    float w = sew[i];
    acc = fmaxf(acc, m[src*C + c]*w);
  }
  agg[nn*C+c] = (e > s) ? acc : 0.f;
}

// ---------------- fused GRU cell: h = GRU(agg, h), 256 threads (R1-proven) ----
template<int C, int NT>
__global__ __launch_bounds__(256) void gru_kernel(
    const float* __restrict__ agg, const float* __restrict__ hin,
    const float* __restrict__ Wih, const float* __restrict__ Whh,
    const float* __restrict__ bih, const float* __restrict__ bhh,
    float* __restrict__ hout, int n_nodes){
  constexpr int G  = 256 / C;
  constexpr int NB = G * NT;
  constexpr int R  = 3 * C;
  constexpr int WLD = R + 1;            // +1 pad: conflict-free transposed WRITE
  __shared__ float WT[C * WLD];         // W^T: [k][r]
  __shared__ float stage[NB * C];
  int tid = threadIdx.x;
  int c = tid % C;
  int g = tid / C;
  int base = blockIdx.x * NB;

  float giR[NT], giZ[NT], giN[NT];
  float ghR[NT], ghZ[NT], ghN[NT];

  // ---- phase 1: gi = agg @ Wih^T + bih ----
  for (int idx=tid; idx<C*R; idx+=256){
    int r = idx / C, k = idx % C;
    WT[k*WLD + r] = Wih[idx];
  }
  for (int idx=tid; idx<NB*C; idx+=256){
    int node = base + idx / C;
    stage[idx] = (node < n_nodes) ? agg[node*C + (idx % C)] : 0.f;
  }
  __syncthreads();
  {
    float b0 = bih[c], b1 = bih[c+C], b2 = bih[c+2*C];
    #pragma unroll
    for (int j=0;j<NT;j++){ giR[j]=b0; giZ[j]=b1; giN[j]=b2; }
    for (int k=0;k<C;k++){
      float wr = WT[k*WLD + c], wz = WT[k*WLD + c + C], wn = WT[k*WLD + c + 2*C];
      #pragma unroll
      for (int j=0;j<NT;j++){
        float a = stage[(g*NT+j)*C + k];
        giR[j] = fmaf(a,wr,giR[j]);
        giZ[j] = fmaf(a,wz,giZ[j]);
        giN[j] = fmaf(a,wn,giN[j]);
      }
    }
  }
  __syncthreads();
  // ---- phase 2: gh = h @ Whh^T + bhh ----
  for (int idx=tid; idx<C*R; idx+=256){
    int r = idx / C, k = idx % C;
    WT[k*WLD + r] = Whh[idx];
  }
  for (int idx=tid; idx<NB*C; idx+=256){
    int node = base + idx / C;
    stage[idx] = (node < n_nodes) ? hin[node*C + (idx % C)] : 0.f;
  }
  __syncthreads();
  {
    float b0 = bhh[c], b1 = bhh[c+C], b2 = bhh[c+2*C];
    #pragma unroll
    for (int j=0;j<NT;j++){ ghR[j]=b0; ghZ[j]=b1; ghN[j]=b2; }
    for (int k=0;k<C;k++){
      float wr = WT[k*WLD + c], wz = WT[k*WLD + c + C], wn = WT[k*WLD + c + 2*C];
      #pragma unroll
      for (int j=0;j<NT;j++){
        float a = stage[(g*NT+j)*C + k];
        ghR[j] = fmaf(a,wr,ghR[j]);
        ghZ[j] = fmaf(a,wz,ghZ[j]);
        ghN[j] = fmaf(a,wn,ghN[j]);
      }
    }
  }
  // ---- gates ----
  #pragma unroll
  for (int j=0;j<NT;j++){
    int node = base + g*NT + j;
    if (node < n_nodes){
      float h  = stage[(g*NT+j)*C + c];
      float r  = sigmoidf_(giR[j] + ghR[j]);
      float z  = sigmoidf_(giZ[j] + ghZ[j]);
      float nn = tanhf(giN[j] + r*ghN[j]);
      hout[node*C + c] = (1.f - z)*nn + z*h;
    }
  }
}

// ---------------- head: elu -> fc1 -> elu -> fc2 -> log_softmax ----------------
__global__ __launch_bounds__(256) void head_kernel(const float* __restrict__ h2,
   const float* __restrict__ fc1w, const float* __restrict__ fc1b,
   const float* __restrict__ fc2w, const float* __restrict__ fc2b,
   float* __restrict__ out, int n){
  __shared__ float W1l[128*64];
  __shared__ float W2l[10*128];
  __shared__ float b1l[128];
  __shared__ float b2l[10];
  int tid = threadIdx.x;
  for (int idx=tid; idx<128*64; idx+=256) W1l[idx]=fc1w[idx];
  for (int idx=tid; idx<10*128; idx+=256) W2l[idx]=fc2w[idx];
  if (tid<128) b1l[tid]=fc1b[tid];
  if (tid<10)  b2l[tid]=fc2b[tid];
  __syncthreads();
  int n0 = blockIdx.x*512 + tid;
  int n1 = n0 + 256;
  bool v0 = n0 < n, v1 = n1 < n;
  float h0[64], h1[64];
  #pragma unroll
  for (int k=0;k<64;k++){
    h0[k] = v0 ? eluf_(h2[n0*64+k]) : 0.f;
    h1[k] = v1 ? eluf_(h2[n1*64+k]) : 0.f;
  }
  float lg0[10], lg1[10];
  #pragma unroll
  for (int c=0;c<10;c++){ lg0[c]=b2l[c]; lg1[c]=b2l[c]; }
  for (int j=0;j<128;j++){
    float s0 = b1l[j], s1 = b1l[j];
    #pragma unroll
    for (int k=0;k<64;k++){
      float w = W1l[j*64+k];
      s0 = fmaf(h0[k], w, s0);
      s1 = fmaf(h1[k], w, s1);
    }
    float e0 = eluf_(s0), e1 = eluf_(s1);
    #pragma unroll
    for (int c=0;c<10;c++){
      float w2 = W2l[c*128+j];
      lg0[c] = fmaf(e0, w2, lg0[c]);
      lg1[c] = fmaf(e1, w2, lg1[c]);
    }
  }
  if (v0){
    float mx = lg0[0];
    #pragma unroll
    for (int c=1;c<10;c++) mx = fmaxf(mx, lg0[c]);
    float s = 0.f;
    #pragma unroll
    for (int c=0;c<10;c++) s += expf(lg0[c]-mx);
    float lse = mx + logf(s);
    #pragma unroll
    for (int c=0;c<10;c++) out[n0*10+c] = lg0[c]-lse;
  }
  if (v1){
    float mx = lg1[0];
    #pragma unroll
    for (int c=1;c<10;c++) mx = fmaxf(mx, lg1[c]);
    float s = 0.f;
    #pragma unroll
    for (int c=0;c<10;c++) s += expf(lg1[c]-mx);
    float lse = mx + logf(s);
    #pragma unroll
    for (int c=0;c<10;c++) out[n1*10+c] = lg1[c]-lse;
  }
}

extern "C" void kernel_launch(void* const* d_in, const int* in_sizes, int n_in,
                              void* d_out, int out_size, void* d_ws, size_t ws_size,
                              hipStream_t stream){
  const float* x    = (const float*)d_in[0];
  const int*   ei   = (const int*)  d_in[1];
  const float* ea   = (const float*)d_in[2];
  const float* W1   = (const float*)d_in[3];
  const float* Wih1 = (const float*)d_in[4];
  const float* Whh1 = (const float*)d_in[5];
  const float* bih1 = (const float*)d_in[6];
  const float* bhh1 = (const float*)d_in[7];
  const float* W2   = (const float*)d_in[8];
  const float* Wih2 = (const float*)d_in[9];
  const float* Whh2 = (const float*)d_in[10];
  const float* bih2 = (const float*)d_in[11];
  const float* bhh2 = (const float*)d_in[12];
  const float* fc1w = (const float*)d_in[13];
  const float* fc1b = (const float*)d_in[14];
  const float* fc2w = (const float*)d_in[15];
  const float* fc2b = (const float*)d_in[16];
  float* outp = (float*)d_out;

  char* ws = (char*)d_ws;
  size_t off = 0;
  auto alloc = [&](size_t bytes)->void*{
    void* p = ws + off;
    off += (bytes + 255) & ~size_t(255);
    return p;
  };
  float* hA        = (float*)alloc(sizeof(float)*N_NODES*64);
  float* hB        = (float*)alloc(sizeof(float)*N_NODES*64);
  float* mB        = (float*)alloc(sizeof(float)*N_NODES*64);
  float* aggB      = (float*)alloc(sizeof(float)*N_NODES*64);
  int*   row_start = (int*)  alloc(sizeof(int)*(N_NODES+1));
  int*   cnt       = (int*)  alloc(sizeof(int)*N_NODES);
  int*   cur       = (int*)  alloc(sizeof(int)*N_NODES);
  int*   pre       = (int*)  alloc(sizeof(int)*N_NODES);
  int*   bsum      = (int*)  alloc(sizeof(int)*1024);
  int*   ssrc      = (int*)  alloc(sizeof(int)*N_EDGES);
  float* sew       = (float*)alloc(sizeof(float)*N_EDGES);
  (void)ws_size; (void)in_sizes; (void)n_in; (void)out_size;

  const int n = N_NODES, e = N_EDGES;
  const int nb = (n + SCAN_BS - 1)/SCAN_BS;   // 391 blocks

  // CSR build (per call; max-agg is order-invariant so atomic ordering is fine)
  zero_counts<<<(n+255)/256,256,0,stream>>>(cnt, cur, n);
  count_kernel<<<(e+255)/256,256,0,stream>>>(ei, cnt, e);
  scan1_kernel<<<nb,SCAN_BS,0,stream>>>(cnt, pre, bsum, n);
  scan2_kernel<<<1,1024,0,stream>>>(bsum, nb);
  scan3_kernel<<<(n+255)/256,256,0,stream>>>(pre, bsum, row_start, n);
  scatter_kernel<<<(e+255)/256,256,0,stream>>>(ei, ea, row_start, cur, ssrc, sew, e);

  // layer 1 (C=32)
  pad_x_kernel<<<(n*32+255)/256,256,0,stream>>>(x, hA, n);
  for (int i=0;i<3;i++){
    mgemm_kernel<32,8><<<(n+127)/128,256,0,stream>>>(hA, W1 + i*32*32, mB, n);
    agg_kernel<32><<<((long long)n*32+255)/256,256,0,stream>>>(mB, row_start, ssrc, sew, aggB, n);
    gru_kernel<32,4><<<(n+31)/32,256,0,stream>>>(aggB, hA, Wih1, Whh1, bih1, bhh1, hA, n);
  }

  // transition: elu + pad 32 -> 64
  transition_kernel<<<(n*64+255)/256,256,0,stream>>>(hA, hB, n);

  // layer 2 (C=64)
  for (int i=0;i<3;i++){
    mgemm_kernel<64,8><<<(n+63)/64,256,0,stream>>>(hB, W2 + i*64*64, mB, n);
    agg_kernel<64><<<((long long)n*64+255)/256,256,0,stream>>>(mB, row_start, ssrc, sew, aggB, n);
    gru_kernel<64,8><<<(n+31)/32,256,0,stream>>>(aggB, hB, Wih2, Whh2, bih2, bhh2, hB, n);
  }

  // head
  head_kernel<<<(n+511)/512,256,0,stream>>>(hB, fc1w, fc1b, fc2w, fc2b, outp, n);
}